// Round 3
// baseline (132.101 us; speedup 1.0000x reference)
//
#include <hip/hip_runtime.h>
#include <math.h>

#define PI_F 3.14159265358979323846f

typedef __attribute__((ext_vector_type(8))) short bh8;    // 8 bf16 in 4 VGPRs
typedef __attribute__((ext_vector_type(4))) float f32x4;  // MFMA accumulator

#define LAG1 12      // LAG-1
#define BB   32
#define NN   1200
#define KPAD 1216    // 1200 padded to 19*64
#define NPAD 1216

// prep block ranges
#define ROW_I4 (KPAD / 8)          // 152 int4 per X row
#define PA_BLK 228                 // 384 rows * 152 int4 / 256
#define PB_BLK 150                 // TI gather: 32*1200 / 256
#define PD_BLK 6                   // zero-pad rows 384..1151 cols 1200..1215
#define PC_BLK 1444                // WT transpose 38*38

__device__ __forceinline__ unsigned short f2bf(float f) {
    unsigned int u = __float_as_uint(f);
    u = (u + 0x7fffu + ((u >> 16) & 1u)) >> 16;
    return (unsigned short)u;
}

__device__ __forceinline__ float gamma_fn_dev(float x) {
    if (x > 0.0f) return expf(lgammaf(x));
    return PI_F / (sinf(PI_F * x) * expf(lgammaf(1.0f - x)));
}

// ---- one prep kernel: X stack + zero-pad + WT transpose ----
__global__ __launch_bounds__(256) void prep_kernel(const float* __restrict__ A,
                                                   const float* __restrict__ TI,
                                                   const float* __restrict__ WW,
                                                   unsigned short* __restrict__ X,
                                                   unsigned short* __restrict__ WT) {
    __shared__ float tile[32][33];
    const int bid = blockIdx.x;
    const int t = threadIdx.x;

    if (bid < PA_BLK) {
        // part A: rows 0..383 (group A), 152 int4 per row
        int idx = bid * 256 + t;                 // 0..58367
        int r = idx / ROW_I4;                    // 0..383
        int c8 = idx - r * ROW_I4;               // 0..151
        int k = c8 * 8;
        unsigned short v[8];
        #pragma unroll
        for (int u = 0; u < 8; u++) {
            int kk = k + u;
            v[u] = (kk < NN) ? f2bf(A[r * NN + kk]) : (unsigned short)0;
        }
        *(int4*)&X[r * KPAD + k] = *(int4*)v;
    } else if (bid < PA_BLK + PB_BLK) {
        // part B: TI gather -> rows 384..1151. thread = (b, i); reads 13 lag
        // values (104B span), scatters 24 bf16 (coalesced across lanes in i)
        int idx = (bid - PA_BLK) * 256 + t;      // 0..38399
        int b = idx / NN, i = idx - b * NN;
        const float* p = TI + (size_t)(b * NN + i) * 26 + 1;  // [...,lg,1]
        float vals[13];
        #pragma unroll
        for (int lg = 0; lg < 13; lg++) vals[lg] = p[lg * 2];
        #pragma unroll
        for (int lag = 0; lag < LAG1; lag++) {
            X[(384 + lag * 32 + b) * KPAD + i] = f2bf(vals[lag]);      // old -> TN
            X[(768 + lag * 32 + b) * KPAD + i] = f2bf(vals[lag + 1]);  // new -> T0
        }
    } else if (bid < PA_BLK + PB_BLK + PD_BLK) {
        // part D: zero-pad cols 1200..1215 for rows 384..1151
        int idx = (bid - PA_BLK - PB_BLK) * 256 + t;  // 0..1535
        if (idx < 768 * 2) {
            int r = idx >> 1, h = idx & 1;
            int4 z = {0, 0, 0, 0};
            *(int4*)&X[(384 + r) * KPAD + 1200 + h * 8] = z;
        }
    } else {
        // part C: WT[j*NPAD+i] = bf16(WW[i*NN+j]), zero-padded
        int cb = bid - (PA_BLK + PB_BLK + PD_BLK);
        int bx = cb % 38, by = cb / 38;
        int i0 = by * 32, j0 = bx * 32;
        int tx = t & 31, ty = t >> 5;            // 32 x 8
        #pragma unroll
        for (int s = 0; s < 32; s += 8) {
            int i = i0 + ty + s, j = j0 + tx;
            tile[ty + s][tx] = (i < NN && j < NN) ? WW[i * NN + j] : 0.0f;
        }
        __syncthreads();
        #pragma unroll
        for (int s = 0; s < 32; s += 8) {
            int j = j0 + ty + s, i = i0 + tx;
            WT[j * NPAD + i] = f2bf(tile[tx][ty + s]);
        }
    }
}

// ---- fused GEMM + tanh + epilogue ----
// Block (lag, bn): M-tile = 96 rows (3 groups x 32 b's of one lag), N-tile = 64.
// 4 waves, wave w owns cols [bn*64 + w*16, +16), 6 m-frags (16x16) each.
// Combines the three group results in registers -> writes `out` directly.
__global__ __launch_bounds__(256) void gemm_fused(const unsigned short* __restrict__ X,
                                                  const unsigned short* __restrict__ WT,
                                                  const float* __restrict__ alpha,
                                                  const float* __restrict__ fract,
                                                  const float* __restrict__ lambd,
                                                  const float* __restrict__ l,
                                                  float* __restrict__ out) {
    __shared__ unsigned short Xs[96 * 72];   // 72-stride: conflict-benign
    __shared__ unsigned short Bs[64 * 72];
    const int lag = blockIdx.x;              // 0..11
    const int bn  = blockIdx.y;              // 0..18
    const int t = threadIdx.x;
    const int wave = t >> 6, lane = t & 63;
    const int l15 = lane & 15, quad = lane >> 4;

    // per-lag coefficients (redundant per thread; one lag per block)
    float a = alpha[lag], f = fract[lag];
    float ga1 = expf(lgammaf(a + 1.0f));
    float belta = 0.0f;
    const float gk[4] = {1.0f, 1.0f, 2.0f, 6.0f};
    #pragma unroll
    for (int kk = 0; kk < 4; kk++)
        belta += ga1 / (gk[kk] * gamma_fn_dev(a - (float)kk + 1.0f));
    const float c2 = ga1 / (6.0f * gamma_fn_dev(a - 2.0f));
    const float e0 = 2.0f * powf(3.0f, f);
    const float ib = 1.0f / belta;

    const int n0 = bn * 64;
    const int j  = n0 + wave * 16 + l15;     // this lane's output column (fixed)
    const int jm = (j < NN) ? (j % 200) : 0;
    const float lv  = l[lag * 200 + jm];
    const float lam = lambd[lag * 200 + jm];

    f32x4 acc[6] = {};

    for (int k0 = 0; k0 < KPAD; k0 += 64) {
        __syncthreads();
        // stage X: 96 rows x 64 cols -> 768 int4, 3 per thread
        #pragma unroll
        for (int u = 0; u < 3; u++) {
            int idx = t + u * 256;
            int row = idx >> 3, c8 = idx & 7;
            int g = row >> 5, w = row & 31;
            int grow = g * 384 + lag * 32 + w;
            *(int4*)&Xs[row * 72 + c8 * 8] =
                *(const int4*)&X[(size_t)grow * KPAD + k0 + c8 * 8];
        }
        // stage WT: 64 rows x 64 cols -> 512 int4, 2 per thread
        #pragma unroll
        for (int u = 0; u < 2; u++) {
            int idx = t + u * 256;
            int row = idx >> 3, c8 = idx & 7;
            *(int4*)&Bs[row * 72 + c8 * 8] =
                *(const int4*)&WT[(size_t)(n0 + row) * NPAD + k0 + c8 * 8];
        }
        __syncthreads();
        #pragma unroll
        for (int kh = 0; kh < 2; kh++) {
            bh8 bfrag = *(const bh8*)&Bs[(wave * 16 + l15) * 72 + kh * 32 + quad * 8];
            #pragma unroll
            for (int fm = 0; fm < 6; fm++) {
                bh8 afrag = *(const bh8*)&Xs[(fm * 16 + l15) * 72 + kh * 32 + quad * 8];
                acc[fm] = __builtin_amdgcn_mfma_f32_16x16x32_bf16(afrag, bfrag, acc[fm], 0, 0, 0);
            }
        }
    }

    // epilogue: rows fm*16+quad*4+r; groups: acc[0..1]=Tout, [2..3]=TN, [4..5]=T0
    if (j < NN) {
        #pragma unroll
        for (int fp = 0; fp < 2; fp++) {
            #pragma unroll
            for (int r = 0; r < 4; r++) {
                int b = fp * 16 + quad * 4 + r;
                float tA = tanhf(-acc[fp][r]);
                float tN = tanhf(-acc[2 + fp][r]);
                float t0 = tanhf(-acc[4 + fp][r]);
                out[(b * LAG1 + lag) * NN + j] =
                    lam * ib * (e0 * tA + 3.0f * lv * (t0 + c2 * tN));
            }
        }
    }
}

extern "C" void kernel_launch(void* const* d_in, const int* in_sizes, int n_in,
                              void* d_out, int out_size, void* d_ws, size_t ws_size,
                              hipStream_t stream) {
    const float* A     = (const float*)d_in[0];
    const float* WW    = (const float*)d_in[1];
    const float* TI    = (const float*)d_in[2];
    const float* alpha = (const float*)d_in[3];
    const float* fract = (const float*)d_in[4];
    const float* lambd = (const float*)d_in[5];
    const float* l     = (const float*)d_in[6];
    float* out = (float*)d_out;

    unsigned short* X  = (unsigned short*)d_ws;      // 1152*1216 bf16
    unsigned short* WT = X + 1152 * KPAD;            // 1216*1216 bf16

    prep_kernel<<<PA_BLK + PB_BLK + PD_BLK + PC_BLK, 256, 0, stream>>>(A, TI, WW, X, WT);
    gemm_fused<<<dim3(LAG1, 19), 256, 0, stream>>>(X, WT, alpha, fract, lambd, l, out);
}

// Round 4
// 131.240 us; speedup vs baseline: 1.0066x; 1.0066x over previous
//
#include <hip/hip_runtime.h>
#include <math.h>

#define PI_F 3.14159265358979323846f

typedef __attribute__((ext_vector_type(8))) short bh8;    // 8 bf16 in 4 VGPRs
typedef __attribute__((ext_vector_type(4))) float f32x4;  // MFMA accumulator

#define LAG1 12      // LAG-1
#define BB   32
#define NN   1200
#define KPAD 1216    // 1200 padded to 19*64
#define NPAD 1216
#define NITER 19     // KPAD / 64
#define LDSW 70      // LDS row stride (shorts): bank idx ~ 3*l15+4*quad -> <=2-3-way

// prep block ranges
#define ROW_I4 (KPAD / 8)          // 152 int4 per X row
#define PA_BLK 228                 // 384 rows * 152 int4 / 256
#define PB_BLK 150                 // TI gather: 32*1200 / 256
#define PD_BLK 6                   // zero-pad rows 384..1151 cols 1200..1215
#define PC_BLK 1444                // WT transpose 38*38

__device__ __forceinline__ unsigned short f2bf(float f) {
    unsigned int u = __float_as_uint(f);
    u = (u + 0x7fffu + ((u >> 16) & 1u)) >> 16;
    return (unsigned short)u;
}

__device__ __forceinline__ float gamma_fn_dev(float x) {
    if (x > 0.0f) return expf(lgammaf(x));
    return PI_F / (sinf(PI_F * x) * expf(lgammaf(1.0f - x)));
}

// ---- one prep kernel: X stack + zero-pad + WT transpose ----
__global__ __launch_bounds__(256) void prep_kernel(const float* __restrict__ A,
                                                   const float* __restrict__ TI,
                                                   const float* __restrict__ WW,
                                                   unsigned short* __restrict__ X,
                                                   unsigned short* __restrict__ WT) {
    __shared__ float tile[32][33];
    const int bid = blockIdx.x;
    const int t = threadIdx.x;

    if (bid < PA_BLK) {
        // part A: rows 0..383 (group A), 152 int4 per row
        int idx = bid * 256 + t;                 // 0..58367
        int r = idx / ROW_I4;                    // 0..383
        int c8 = idx - r * ROW_I4;               // 0..151
        int k = c8 * 8;
        unsigned short v[8];
        #pragma unroll
        for (int u = 0; u < 8; u++) {
            int kk = k + u;
            v[u] = (kk < NN) ? f2bf(A[r * NN + kk]) : (unsigned short)0;
        }
        *(int4*)&X[r * KPAD + k] = *(int4*)v;
    } else if (bid < PA_BLK + PB_BLK) {
        // part B: TI gather -> rows 384..1151. thread = (b, i)
        int idx = (bid - PA_BLK) * 256 + t;      // 0..38399
        int b = idx / NN, i = idx - b * NN;
        const float* p = TI + (size_t)(b * NN + i) * 26 + 1;  // [...,lg,1]
        float vals[13];
        #pragma unroll
        for (int lg = 0; lg < 13; lg++) vals[lg] = p[lg * 2];
        #pragma unroll
        for (int lag = 0; lag < LAG1; lag++) {
            X[(384 + lag * 32 + b) * KPAD + i] = f2bf(vals[lag]);      // old -> TN
            X[(768 + lag * 32 + b) * KPAD + i] = f2bf(vals[lag + 1]);  // new -> T0
        }
    } else if (bid < PA_BLK + PB_BLK + PD_BLK) {
        // part D: zero-pad cols 1200..1215 for rows 384..1151
        int idx = (bid - PA_BLK - PB_BLK) * 256 + t;  // 0..1535
        if (idx < 768 * 2) {
            int r = idx >> 1, h = idx & 1;
            int4 z = {0, 0, 0, 0};
            *(int4*)&X[(384 + r) * KPAD + 1200 + h * 8] = z;
        }
    } else {
        // part C: WT[j*NPAD+i] = bf16(WW[i*NN+j]), zero-padded
        int cb = bid - (PA_BLK + PB_BLK + PD_BLK);
        int bx = cb % 38, by = cb / 38;
        int i0 = by * 32, j0 = bx * 32;
        int tx = t & 31, ty = t >> 5;            // 32 x 8
        #pragma unroll
        for (int s = 0; s < 32; s += 8) {
            int i = i0 + ty + s, j = j0 + tx;
            tile[ty + s][tx] = (i < NN && j < NN) ? WW[i * NN + j] : 0.0f;
        }
        __syncthreads();
        #pragma unroll
        for (int s = 0; s < 32; s += 8) {
            int j = j0 + ty + s, i = i0 + tx;
            WT[j * NPAD + i] = f2bf(tile[tx][ty + s]);
        }
    }
}

// ---- fused GEMM + tanh + epilogue, double-buffered LDS + register prefetch ----
// Block (lag, bn): M-tile = 96 rows (3 groups x 32 b's of one lag), N-tile = 64.
// 4 waves; wave w owns cols [bn*64 + w*16, +16), 6 m-frags each.
// One barrier per k-iter; next tile's global loads are in flight during MFMA.
__global__ __launch_bounds__(256) void gemm_fused(const unsigned short* __restrict__ X,
                                                  const unsigned short* __restrict__ WT,
                                                  const float* __restrict__ alpha,
                                                  const float* __restrict__ fract,
                                                  const float* __restrict__ lambd,
                                                  const float* __restrict__ l,
                                                  float* __restrict__ out) {
    __shared__ unsigned short Xs[2][96 * LDSW];
    __shared__ unsigned short Bs[2][64 * LDSW];
    const int lag = blockIdx.x;              // 0..11
    const int bn  = blockIdx.y;              // 0..18
    const int t = threadIdx.x;
    const int wave = t >> 6, lane = t & 63;
    const int l15 = lane & 15, quad = lane >> 4;
    const int n0 = bn * 64;

    // staging addresses (X: 3 int4/thread, B: 2 int4/thread)
    const unsigned short* gx[3]; int lx[3];
    #pragma unroll
    for (int u = 0; u < 3; u++) {
        int idx = t + u * 256;
        int row = idx >> 3, c8 = idx & 7;
        int grow = (row >> 5) * 384 + lag * 32 + (row & 31);
        gx[u] = X + (size_t)grow * KPAD + c8 * 8;
        lx[u] = row * LDSW + c8 * 8;
    }
    const unsigned short* gb[2]; int lb[2];
    #pragma unroll
    for (int u = 0; u < 2; u++) {
        int idx = t + u * 256;
        int row = idx >> 3, c8 = idx & 7;
        gb[u] = WT + (size_t)(n0 + row) * NPAD + c8 * 8;
        lb[u] = row * LDSW + c8 * 8;
    }

    // prologue: load tile 0 into registers (in flight during coef math below)
    int4 xr[3], br[2];
    #pragma unroll
    for (int u = 0; u < 3; u++) xr[u] = *(const int4*)(gx[u]);
    #pragma unroll
    for (int u = 0; u < 2; u++) br[u] = *(const int4*)(gb[u]);

    // per-lag coefficients (redundant per thread; one lag per block)
    float a = alpha[lag], f = fract[lag];
    float ga1 = expf(lgammaf(a + 1.0f));
    float belta = 0.0f;
    const float gk[4] = {1.0f, 1.0f, 2.0f, 6.0f};
    #pragma unroll
    for (int kk = 0; kk < 4; kk++)
        belta += ga1 / (gk[kk] * gamma_fn_dev(a - (float)kk + 1.0f));
    const float c2 = ga1 / (6.0f * gamma_fn_dev(a - 2.0f));
    const float e0 = 2.0f * powf(3.0f, f);
    const float ib = 1.0f / belta;

    const int j  = n0 + wave * 16 + l15;     // this lane's output column (fixed)
    const int jm = (j < NN) ? (j % 200) : 0;
    const float lv  = l[lag * 200 + jm];
    const float lam = lambd[lag * 200 + jm];

    f32x4 acc[6] = {};

    for (int it = 0; it < NITER; ++it) {
        const int p = it & 1;
        // drain prefetched regs into LDS buffer p
        #pragma unroll
        for (int u = 0; u < 3; u++) *(int4*)&Xs[p][lx[u]] = xr[u];
        #pragma unroll
        for (int u = 0; u < 2; u++) *(int4*)&Bs[p][lb[u]] = br[u];
        __syncthreads();
        // issue next tile's loads NOW — in flight during the MFMA phase
        if (it + 1 < NITER) {
            const int k1 = (it + 1) * 64;
            #pragma unroll
            for (int u = 0; u < 3; u++) xr[u] = *(const int4*)(gx[u] + k1);
            #pragma unroll
            for (int u = 0; u < 2; u++) br[u] = *(const int4*)(gb[u] + k1);
        }
        // MFMA phase on buffer p
        #pragma unroll
        for (int kh = 0; kh < 2; kh++) {
            bh8 bfrag = *(const bh8*)&Bs[p][(wave * 16 + l15) * LDSW + kh * 32 + quad * 8];
            #pragma unroll
            for (int fm = 0; fm < 6; fm++) {
                bh8 afrag = *(const bh8*)&Xs[p][(fm * 16 + l15) * LDSW + kh * 32 + quad * 8];
                acc[fm] = __builtin_amdgcn_mfma_f32_16x16x32_bf16(afrag, bfrag, acc[fm], 0, 0, 0);
            }
        }
        // no second barrier: write(i+1) targets the buffer last read at i-1,
        // which barrier(i) proves drained (MFMA(i-1) precedes write(i) in
        // every wave's program order).
    }

    // epilogue: rows fm*16+quad*4+r; groups: acc[0..1]=Tout, [2..3]=TN, [4..5]=T0
    if (j < NN) {
        #pragma unroll
        for (int fp = 0; fp < 2; fp++) {
            #pragma unroll
            for (int r = 0; r < 4; r++) {
                int b = fp * 16 + quad * 4 + r;
                float tA = tanhf(-acc[fp][r]);
                float tN = tanhf(-acc[2 + fp][r]);
                float t0 = tanhf(-acc[4 + fp][r]);
                out[(b * LAG1 + lag) * NN + j] =
                    lam * ib * (e0 * tA + 3.0f * lv * (t0 + c2 * tN));
            }
        }
    }
}

extern "C" void kernel_launch(void* const* d_in, const int* in_sizes, int n_in,
                              void* d_out, int out_size, void* d_ws, size_t ws_size,
                              hipStream_t stream) {
    const float* A     = (const float*)d_in[0];
    const float* WW    = (const float*)d_in[1];
    const float* TI    = (const float*)d_in[2];
    const float* alpha = (const float*)d_in[3];
    const float* fract = (const float*)d_in[4];
    const float* lambd = (const float*)d_in[5];
    const float* l     = (const float*)d_in[6];
    float* out = (float*)d_out;

    unsigned short* X  = (unsigned short*)d_ws;      // 1152*1216 bf16
    unsigned short* WT = X + 1152 * KPAD;            // 1216*1216 bf16

    prep_kernel<<<PA_BLK + PB_BLK + PD_BLK + PC_BLK, 256, 0, stream>>>(A, TI, WW, X, WT);
    gemm_fused<<<dim3(LAG1, 19), 256, 0, stream>>>(X, WT, alpha, fract, lambd, l, out);
}

// Round 5
// 104.116 us; speedup vs baseline: 1.2688x; 1.2605x over previous
//
#include <hip/hip_runtime.h>
#include <math.h>

#define PI_F 3.14159265358979323846f

typedef __attribute__((ext_vector_type(8))) short bh8;    // 8 bf16 in 4 VGPRs
typedef __attribute__((ext_vector_type(4))) float f32x4;  // MFMA accumulator

#define LAG1 12      // LAG-1
#define BB   32
#define NN   1200
#define KPAD 1216    // 1200 padded to 19*64
#define NPAD 1216
#define NITER 19     // KPAD / 64
#define KS0   10     // k-iters in split-K slice 0 (slice 1 gets 9)
#define LDSW  72     // LDS row stride in shorts — 144B, 16B-aligned (LDSW=70 broke b128 alignment)

// X row layout (interleaved for in-register group fusion):
//   row = lag*96 + (b>>4)*48 + g*16 + (b&15),  g: 0=A(Tout) 1=old(TN) 2=new(T0)
// => wave (mh = b-half) owns 3 contiguous-frag groups for the same 16 b's.

// prep block ranges
#define ROW_I4 (KPAD / 8)          // 152 int4 per X row
#define PA_BLK 228                 // A copy: 384 rows * 152 int4 / 256
#define PB_BLK 150                 // TI gather: 32*1200 / 256
#define PD_BLK 6                   // zero-pad g1/g2 rows cols 1200..1215
#define PC_BLK 1444                // WT transpose 38*38
#define PE_BLK 1                   // coef
#define PREP_BLOCKS (PA_BLK + PB_BLK + PD_BLK + PC_BLK + PE_BLK)

__device__ __forceinline__ unsigned short f2bf(float f) {
    unsigned int u = __float_as_uint(f);
    u = (u + 0x7fffu + ((u >> 16) & 1u)) >> 16;
    return (unsigned short)u;
}

__device__ __forceinline__ float gamma_fn_dev(float x) {
    if (x > 0.0f) return expf(lgammaf(x));
    return PI_F / (sinf(PI_F * x) * expf(lgammaf(1.0f - x)));
}

// ---- prep: X stack (interleaved rows) + pads + WT transpose + coefs ----
__global__ __launch_bounds__(256) void prep_kernel(const float* __restrict__ A,
                                                   const float* __restrict__ TI,
                                                   const float* __restrict__ WW,
                                                   const float* __restrict__ alpha,
                                                   const float* __restrict__ fract,
                                                   unsigned short* __restrict__ X,
                                                   unsigned short* __restrict__ WT,
                                                   float* __restrict__ coef) {
    __shared__ float tile[32][33];
    const int bid = blockIdx.x;
    const int t = threadIdx.x;

    if (bid < PA_BLK) {
        // part A: A[lag*32+b, k] -> X row lag*96 + (b>>4)*48 + (b&15)
        int idx = bid * 256 + t;                 // 0..58367
        int ra = idx / ROW_I4;                   // 0..383 (= lag*32+b)
        int c8 = idx - ra * ROW_I4;              // 0..151
        int k = c8 * 8;
        int row = (ra >> 5) * 96 + ((ra >> 4) & 1) * 48 + (ra & 15);
        unsigned short v[8];
        #pragma unroll
        for (int u = 0; u < 8; u++) {
            int kk = k + u;
            v[u] = (kk < NN) ? f2bf(A[ra * NN + kk]) : (unsigned short)0;
        }
        *(int4*)&X[row * KPAD + k] = *(int4*)v;
    } else if (bid < PA_BLK + PB_BLK) {
        // part B: TI gather; thread = (b, i)
        int idx = (bid - PA_BLK) * 256 + t;      // 0..38399
        int b = idx / NN, i = idx - b * NN;
        const float* p = TI + (size_t)(b * NN + i) * 26 + 1;  // [...,lg,1]
        float vals[13];
        #pragma unroll
        for (int lg = 0; lg < 13; lg++) vals[lg] = p[lg * 2];
        int rbase = (b >> 4) * 48 + (b & 15);
        #pragma unroll
        for (int lag = 0; lag < LAG1; lag++) {
            X[(lag * 96 + rbase + 16) * KPAD + i] = f2bf(vals[lag]);      // g1 old -> TN
            X[(lag * 96 + rbase + 32) * KPAD + i] = f2bf(vals[lag + 1]);  // g2 new -> T0
        }
    } else if (bid < PA_BLK + PB_BLK + PD_BLK) {
        // part D: zero-pad cols 1200..1215 for the 768 g1/g2 rows
        int idx = (bid - PA_BLK - PB_BLK) * 256 + t;  // 0..1535
        if (idx < 768 * 2) {
            int pr = idx >> 1, h = idx & 1;
            int lag = pr / 64, rem = pr - lag * 64;
            int half = rem >> 5, gi = (rem >> 4) & 1, b16 = rem & 15;
            int row = lag * 96 + half * 48 + 16 + gi * 16 + b16;
            int4 z = {0, 0, 0, 0};
            *(int4*)&X[row * KPAD + 1200 + h * 8] = z;
        }
    } else if (bid < PA_BLK + PB_BLK + PD_BLK + PC_BLK) {
        // part C: WT[j*NPAD+i] = bf16(WW[i*NN+j]), zero-padded
        int cb = bid - (PA_BLK + PB_BLK + PD_BLK);
        int bx = cb % 38, by = cb / 38;
        int i0 = by * 32, j0 = bx * 32;
        int tx = t & 31, ty = t >> 5;            // 32 x 8
        #pragma unroll
        for (int s = 0; s < 32; s += 8) {
            int i = i0 + ty + s, j = j0 + tx;
            tile[ty + s][tx] = (i < NN && j < NN) ? WW[i * NN + j] : 0.0f;
        }
        __syncthreads();
        #pragma unroll
        for (int s = 0; s < 32; s += 8) {
            int j = j0 + ty + s, i = i0 + tx;
            WT[j * NPAD + i] = f2bf(tile[tx][ty + s]);
        }
    } else {
        // part E: per-lag coefficients
        int lag = t;
        if (lag < LAG1) {
            float a = alpha[lag], f = fract[lag];
            float ga1 = expf(lgammaf(a + 1.0f));
            float belta = 0.0f;
            const float gk[4] = {1.0f, 1.0f, 2.0f, 6.0f};
            #pragma unroll
            for (int kk = 0; kk < 4; kk++)
                belta += ga1 / (gk[kk] * gamma_fn_dev(a - (float)kk + 1.0f));
            coef[lag]      = 2.0f * powf(3.0f, f);               // e0
            coef[12 + lag] = ga1 / (6.0f * gamma_fn_dev(a - 2.0f)); // c2
            coef[24 + lag] = 1.0f / belta;                        // 1/belta
        }
    }
}

// ---- split-K GEMM: 512 threads, 8 waves; wave = (mh = b-half, nq = 16-col slice) ----
// Block (bn, ks, lag). Stores raw partial sums to P[ks] (no tanh here).
__global__ __launch_bounds__(512) void gemm_splitk(const unsigned short* __restrict__ X,
                                                   const unsigned short* __restrict__ WT,
                                                   float* __restrict__ P) {
    __shared__ unsigned short Xs[2][96 * LDSW];
    __shared__ unsigned short Bs[2][64 * LDSW];
    const int bn = blockIdx.x, ks = blockIdx.y, lag = blockIdx.z;
    const int t = threadIdx.x;
    const int wave = t >> 6, lane = t & 63;
    const int l15 = lane & 15, quad = lane >> 4;
    const int mh = wave >> 2, nq = wave & 3;
    const int n0 = bn * 64;
    const int itStart = ks ? KS0 : 0;
    const int itEnd   = ks ? NITER : KS0;

    // staging addresses: X rows 0..63 by all 512, rows 64..95 by t<256 (wave-uniform)
    const int row0 = t >> 3, c80 = (t & 7) * 8;
    const unsigned short* gx0 = X + (size_t)(lag * 96 + row0) * KPAD + c80;
    const unsigned short* gx1 = X + (size_t)(lag * 96 + 64 + row0) * KPAD + c80;
    const unsigned short* gb0 = WT + (size_t)(n0 + row0) * NPAD + c80;
    const int lx0 = row0 * LDSW + c80;
    const int lx1 = (64 + row0) * LDSW + c80;

    int4 xr0, xr1, br0;
    {
        const int k0 = itStart * 64;
        xr0 = *(const int4*)(gx0 + k0);
        if (t < 256) xr1 = *(const int4*)(gx1 + k0);
        br0 = *(const int4*)(gb0 + k0);
    }

    f32x4 acc[3] = {};   // g0=Tout, g1=TN(old), g2=T0(new) partial sums

    for (int it = itStart; it < itEnd; ++it) {
        const int p = (it - itStart) & 1;
        *(int4*)&Xs[p][lx0] = xr0;
        if (t < 256) *(int4*)&Xs[p][lx1] = xr1;
        *(int4*)&Bs[p][lx0] = br0;     // same lane->offset formula as X rows 0..63
        __syncthreads();
        if (it + 1 < itEnd) {
            const int k1 = (it + 1) * 64;
            xr0 = *(const int4*)(gx0 + k1);
            if (t < 256) xr1 = *(const int4*)(gx1 + k1);
            br0 = *(const int4*)(gb0 + k1);
        }
        #pragma unroll
        for (int kh = 0; kh < 2; kh++) {
            bh8 bfrag = *(const bh8*)&Bs[p][(nq * 16 + l15) * LDSW + kh * 32 + quad * 8];
            #pragma unroll
            for (int g = 0; g < 3; g++) {
                bh8 afrag = *(const bh8*)&Xs[p][(mh * 48 + g * 16 + l15) * LDSW + kh * 32 + quad * 8];
                acc[g] = __builtin_amdgcn_mfma_f32_16x16x32_bf16(afrag, bfrag, acc[g], 0, 0, 0);
            }
        }
        // single barrier per iter is safe: write(i+1) targets the buffer read at
        // i-1; every wave's MFMA(i-1) precedes its write(i) -> barrier(i) orders it.
    }

    // store partials (C/D layout: col=lane&15, row=quad*4+reg)
    const int j = n0 + nq * 16 + l15;
    if (j < NN) {
        float* Pk = P + (size_t)ks * (1152 * NN);
        #pragma unroll
        for (int g = 0; g < 3; g++) {
            int rowb = lag * 96 + mh * 48 + g * 16 + quad * 4;
            #pragma unroll
            for (int r = 0; r < 4; r++)
                Pk[(size_t)(rowb + r) * NN + j] = acc[g][r];
        }
    }
}

// ---- combine: sum split-K partials, tanh, coefficient algebra, write out ----
__global__ __launch_bounds__(256) void combine_kernel(const float* __restrict__ P,
                                                      const float* __restrict__ coef,
                                                      const float* __restrict__ lambd,
                                                      const float* __restrict__ l,
                                                      float* __restrict__ out) {
    int idx = blockIdx.x * 256 + threadIdx.x;
    if (idx >= BB * LAG1 * NN) return;
    int j = idx % NN;
    int t2 = idx / NN;
    int lag = t2 % LAG1, b = t2 / LAG1;
    int base = lag * 96 + (b >> 4) * 48 + (b & 15);
    const float* P1 = P + (size_t)1152 * NN;
    float s0 = P[(size_t)base * NN + j]        + P1[(size_t)base * NN + j];
    float s1 = P[(size_t)(base + 16) * NN + j] + P1[(size_t)(base + 16) * NN + j];
    float s2 = P[(size_t)(base + 32) * NN + j] + P1[(size_t)(base + 32) * NN + j];
    int jm = j % 200;
    float lv  = l[lag * 200 + jm];
    float lam = lambd[lag * 200 + jm];
    float e0 = coef[lag], c2 = coef[12 + lag], ib = coef[24 + lag];
    out[idx] = lam * ib * (e0 * tanhf(-s0) + 3.0f * lv * (tanhf(-s2) + c2 * tanhf(-s1)));
}

extern "C" void kernel_launch(void* const* d_in, const int* in_sizes, int n_in,
                              void* d_out, int out_size, void* d_ws, size_t ws_size,
                              hipStream_t stream) {
    const float* A     = (const float*)d_in[0];
    const float* WW    = (const float*)d_in[1];
    const float* TI    = (const float*)d_in[2];
    const float* alpha = (const float*)d_in[3];
    const float* fract = (const float*)d_in[4];
    const float* lambd = (const float*)d_in[5];
    const float* l     = (const float*)d_in[6];
    float* out = (float*)d_out;

    unsigned short* X  = (unsigned short*)d_ws;      // 1152*1216 bf16
    unsigned short* WT = X + 1152 * KPAD;            // 1216*1216 bf16
    float* P    = (float*)(WT + (size_t)NPAD * NPAD);// 2 * 1152*1200 f32 partials
    float* coef = P + (size_t)2 * 1152 * NN;         // 36 f32

    prep_kernel<<<PREP_BLOCKS, 256, 0, stream>>>(A, TI, WW, alpha, fract, X, WT, coef);
    gemm_splitk<<<dim3(19, 2, LAG1), 512, 0, stream>>>(X, WT, P);
    combine_kernel<<<(BB * LAG1 * NN + 255) / 256, 256, 0, stream>>>(P, coef, lambd, l, out);
}